// Round 3
// baseline (163.260 us; speedup 1.0000x reference)
//
#include <hip/hip_runtime.h>
#include <hip/hip_bf16.h>

#define B_ 1024
#define S_ 100
#define IN_ 100
#define H_ 128
#define MID_ 32
#define OUT_ 2
#define P_ (B_ * S_)
#define RSQRT_H 0.08838834764831845f
#define LSTR 136     // LDS row stride (bf16): 272 B = 17*16 -> b128-aligned, odd*16 banks
#define TILE 25      // center rows per block (4 tiles per sequence)
#define KR 32        // klds rows (x -> kq -> nsum -> mid), 2 M-tiles
#define HR 34        // hlds rows (h -> ctx): halo rows 0..28 valid + A-read overrun to 33

typedef __attribute__((ext_vector_type(8))) short short8;
typedef __attribute__((ext_vector_type(4))) float float4v;

__device__ __forceinline__ float bf2f(ushort u) {
    union { unsigned u; float f; } c; c.u = ((unsigned)u) << 16; return c.f;
}
__device__ __forceinline__ ushort f2bf(float x) {
    union { float f; unsigned u; } c; c.f = x;
    unsigned r = c.u + 0x7FFFu + ((c.u >> 16) & 1u);  // RNE
    return (ushort)(r >> 16);
}

// ---------------------------------------------------------------------------
// Merged prep (160 blocks):
//  blocks 0..143: W1T[n][k]=W1[k][n] (k>=100 -> 0), WvT, W2T  (bf16, [n][128])
//  blocks 144..159: WqkT[n][k] = sum_j Wq[k][j]*Wk[n][j]      (bf16, [n][128])
// ---------------------------------------------------------------------------
__global__ __launch_bounds__(256) void prep_kernel(const float* __restrict__ W1,
                                                   const float* __restrict__ Wv,
                                                   const float* __restrict__ W2,
                                                   const float* __restrict__ Wq,
                                                   const float* __restrict__ Wk,
                                                   ushort* __restrict__ W1T,
                                                   ushort* __restrict__ WvT,
                                                   ushort* __restrict__ W2T,
                                                   ushort* __restrict__ WqkT) {
    int tid = threadIdx.x;
    if (blockIdx.x < 144) {
        int g = blockIdx.x * 256 + tid;
        if (g < 16384) {
            int n = g >> 7, k = g & 127;
            W1T[g] = (k < IN_) ? f2bf(W1[k * H_ + n]) : (ushort)0;
        } else if (g < 32768) {
            int e = g - 16384; int n = e >> 7, k = e & 127;
            WvT[e] = f2bf(Wv[k * H_ + n]);
        } else {
            int e = g - 32768; int n = e >> 7, k = e & 127;
            W2T[e] = f2bf(W2[k * MID_ + n]);
        }
    } else {
        __shared__ float sq[32][132];
        __shared__ float sk[32][132];
        int bb = blockIdx.x - 144;
        int n0 = (bb >> 2) * 32, k0 = (bb & 3) * 32;
        for (int i = tid; i < 32 * 128; i += 256) {
            int r = i >> 7, c = i & 127;
            sq[r][c] = Wq[(k0 + r) * H_ + c];
            sk[r][c] = Wk[(n0 + r) * H_ + c];
        }
        __syncthreads();
        for (int i = tid; i < 1024; i += 256) {
            int kk = i & 31, nn = i >> 5;
            float a = 0.f;
            for (int j = 0; j < 128; ++j) a += sq[kk][j] * sk[nn][j];
            WqkT[(n0 + nn) * 128 + (k0 + kk)] = f2bf(a);
        }
    }
}

// ---------------------------------------------------------------------------
// 2-M-tile fused GEMM stage: C[m][n] = epi(A[abase+m][0:128] @ WT^T), m in 0..31
// wave owns N-tiles {2w,2w+1} (N=128). EPI 0: none | 1: relu(+b)+pe, invalid
// seq rows -> 0 | 2: +b
// ---------------------------------------------------------------------------
template <int EPI>
__device__ __forceinline__ void mm2(const ushort* __restrict__ A, int abase,
                                    const ushort* __restrict__ WT,
                                    ushort* __restrict__ C,
                                    int wave, int lane,
                                    const float* __restrict__ bias,
                                    const float* __restrict__ pe, int srow0) {
    int l15 = lane & 15, quad = lane >> 4;
    short8 bfrag[2][4];
#pragma unroll
    for (int nt = 0; nt < 2; ++nt) {
        int n = (wave * 2 + nt) * 16 + l15;
#pragma unroll
        for (int ks = 0; ks < 4; ++ks)
            bfrag[nt][ks] = *(const short8*)(WT + n * 128 + ks * 32 + quad * 8);
    }
    float biasv[2] = {0.f, 0.f};
    if (EPI != 0) {
#pragma unroll
        for (int nt = 0; nt < 2; ++nt) biasv[nt] = bias[(wave * 2 + nt) * 16 + l15];
    }
#pragma unroll
    for (int mt = 0; mt < 2; ++mt) {
        short8 afrag[4];
#pragma unroll
        for (int ks = 0; ks < 4; ++ks)
            afrag[ks] = *(const short8*)(A + (abase + mt * 16 + l15) * LSTR + ks * 32 + quad * 8);
#pragma unroll
        for (int nt = 0; nt < 2; ++nt) {
            float4v acc = {0.f, 0.f, 0.f, 0.f};
#pragma unroll
            for (int ks = 0; ks < 4; ++ks)
                acc = __builtin_amdgcn_mfma_f32_16x16x32_bf16(afrag[ks], bfrag[nt][ks], acc, 0, 0, 0);
            int n = (wave * 2 + nt) * 16 + l15;
#pragma unroll
            for (int i = 0; i < 4; ++i) {
                int row = mt * 16 + quad * 4 + i;
                float v = acc[i];
                if (EPI == 1) {
                    int srow = srow0 + row;
                    v = (srow >= 0 && srow < S_)
                            ? (fmaxf(v + biasv[nt], 0.f) + pe[srow * H_ + n]) : 0.f;
                } else if (EPI == 2) v = v + biasv[nt];
                C[row * LSTR + n] = f2bf(v);
            }
        }
    }
}

// ---------------------------------------------------------------------------
// Fused kernel: 4096 blocks; block = (sequence b, tile t of 25 rows + halo 2).
// ---------------------------------------------------------------------------
__global__ __launch_bounds__(256, 5) void fused_kernel(
    const float* __restrict__ x, const ushort* __restrict__ W1T,
    const ushort* __restrict__ WqkT, const ushort* __restrict__ WvT,
    const ushort* __restrict__ W2T,
    const float* __restrict__ b1, const float* __restrict__ bv,
    const float* __restrict__ b2, const float* __restrict__ W3,
    const float* __restrict__ b3, const float* __restrict__ pe,
    float* __restrict__ out, float* __restrict__ wout) {
    __shared__ ushort klds[KR * LSTR];  // x -> kq -> nsum -> mid
    __shared__ ushort hlds[HR * LSTR];  // h -> ctx
    __shared__ float warr[TILE * 5];    // softmax weights staging

    int tid = threadIdx.x, wave = tid >> 6, lane = tid & 63;
    int b = blockIdx.x >> 2, t = blockIdx.x & 3;
    int r0 = t * TILE;
    int srow0 = r0 - 2;  // seq row of klds/hlds local row 0

    // --- zero pad regions (disjoint from x writes -> no barrier needed between)
    for (int i = tid; i < 29 * 18; i += 256) {          // klds rows 0..28, cols 100..135
        int r = i / 18, c = 100 + 2 * (i - r * 18);
        *(uint*)(klds + r * LSTR + c) = 0u;
    }
    for (int i = tid; i < 3 * 68; i += 256) {           // klds rows 29..31 full
        int r = 29 + i / 68, c = 2 * (i % 68);
        *(uint*)(klds + r * LSTR + c) = 0u;
    }
    for (int i = tid; i < 2 * 68; i += 256) {           // hlds rows 32..33 full
        int r = 32 + i / 68, c = 2 * (i % 68);
        *(uint*)(hlds + r * LSTR + c) = 0u;
    }
    // --- stage x tile (rows max(r0-2,0) .. min(r0+27,100)) as bf16
    {
        int g0 = srow0 < 0 ? 0 : srow0;
        int g1 = (r0 + 27 < S_) ? (r0 + 27) : S_;
        int lr0 = g0 - srow0;
        const float* xb = x + ((size_t)b * S_ + g0) * IN_;
        int pairs = (g1 - g0) * 50;
        for (int p = tid; p < pairs; p += 256) {
            int row = p / 50;
            int c2 = (p - row * 50) * 2;
            const float* src = xb + row * IN_ + c2;
            uint pk = ((uint)f2bf(src[1]) << 16) | (uint)f2bf(src[0]);
            *(uint*)(klds + (lr0 + row) * LSTR + c2) = pk;
        }
    }
    __syncthreads();
    // S1: h = relu(x@W1+b1)+pe -> hlds rows 0..31 (invalid seq rows -> 0)
    mm2<1>(klds, 0, W1T, hlds, wave, lane, b1, pe, srow0);
    __syncthreads();
    // S2: kq = h @ (Wq Wk^T) -> klds rows 0..31 (center row c at klds row c)
    mm2<0>(hlds, 2, WqkT, klds, wave, lane, nullptr, nullptr, 0);
    __syncthreads();
    // S3: scores -> softmax -> w (warr) + nsum in-place over klds rows 0..24
    if (tid < TILE * 8) {
        int r = tid >> 3, sub = tid & 7;  // 8 threads/row, 16 dims each
        const ushort* kqr = klds + r * LSTR + sub * 16;
        float kqf[16];
#pragma unroll
        for (int c = 0; c < 2; ++c) {
            short8 v = *(const short8*)(kqr + c * 8);
#pragma unroll
            for (int j = 0; j < 8; ++j) kqf[c * 8 + j] = bf2f((ushort)v[j]);
        }
        float sc[5];
#pragma unroll
        for (int m = 0; m < 5; ++m) {
            int gs = r0 + r + 2 - m;   // neighbor m == x[i + ATTEN - m]
            float p = 0.f;
            if (gs >= 0 && gs < S_) {
                const ushort* hr = hlds + (r + 4 - m) * LSTR + sub * 16;
#pragma unroll
                for (int c = 0; c < 2; ++c) {
                    short8 v = *(const short8*)(hr + c * 8);
#pragma unroll
                    for (int j = 0; j < 8; ++j) p += bf2f((ushort)v[j]) * kqf[c * 8 + j];
                }
            }
            sc[m] = p;
        }
#pragma unroll
        for (int m = 0; m < 5; ++m) {
            sc[m] += __shfl_xor(sc[m], 1);
            sc[m] += __shfl_xor(sc[m], 2);
            sc[m] += __shfl_xor(sc[m], 4);
            sc[m] *= RSQRT_H;
        }
        float mx = sc[0];
#pragma unroll
        for (int m = 1; m < 5; ++m) mx = fmaxf(mx, sc[m]);
        float e[5], ss = 0.f;
#pragma unroll
        for (int m = 0; m < 5; ++m) { e[m] = __expf(sc[m] - mx); ss += e[m]; }
        float inv = 1.f / ss;
        float w5[5];
#pragma unroll
        for (int m = 0; m < 5; ++m) w5[m] = e[m] * inv;
        if (sub == 0) {
#pragma unroll
            for (int m = 0; m < 5; ++m) warr[r * 5 + m] = w5[m];
        }
        float acc[16];
#pragma unroll
        for (int c = 0; c < 16; ++c) acc[c] = 0.f;
#pragma unroll
        for (int m = 0; m < 5; ++m) {
            int gs = r0 + r + 2 - m;
            if (gs < 0 || gs >= S_) continue;
            float wm = w5[m];
            const ushort* hr = hlds + (r + 4 - m) * LSTR + sub * 16;
#pragma unroll
            for (int c = 0; c < 2; ++c) {
                short8 v = *(const short8*)(hr + c * 8);
#pragma unroll
                for (int j = 0; j < 8; ++j) acc[c * 8 + j] += wm * bf2f((ushort)v[j]);
            }
        }
        ushort* op = klds + r * LSTR + sub * 16;  // own chunk only: race-free
#pragma unroll
        for (int c = 0; c < 2; ++c) {
            short8 v;
#pragma unroll
            for (int j = 0; j < 8; ++j) v[j] = (short)f2bf(acc[c * 8 + j]);
            *(short8*)(op + c * 8) = v;
        }
    }
    __syncthreads();
    // w -> global (coalesced), independent of S4 MFMA below
    if (tid < TILE * 5)
        wout[(size_t)b * (S_ * 5) + r0 * 5 + tid] = warr[tid];
    // S4: ctx = nsum @ Wv + bv -> hlds rows 0..31
    mm2<2>(klds, 0, WvT, hlds, wave, lane, bv, nullptr, 0);
    __syncthreads();
    // S5: mid = relu(ctx@W2+b2) -> klds cols 0..31; wave -> (mt, nt) in {0,1}^2
    {
        int l15 = lane & 15, quad = lane >> 4;
        int mt = wave & 1, nt = wave >> 1;
        short8 bfrag[4];
#pragma unroll
        for (int ks = 0; ks < 4; ++ks)
            bfrag[ks] = *(const short8*)(W2T + (nt * 16 + l15) * 128 + ks * 32 + quad * 8);
        float bias2 = b2[nt * 16 + l15];
        short8 afrag[4];
#pragma unroll
        for (int ks = 0; ks < 4; ++ks)
            afrag[ks] = *(const short8*)(hlds + (mt * 16 + l15) * LSTR + ks * 32 + quad * 8);
        float4v acc = {0.f, 0.f, 0.f, 0.f};
#pragma unroll
        for (int ks = 0; ks < 4; ++ks)
            acc = __builtin_amdgcn_mfma_f32_16x16x32_bf16(afrag[ks], bfrag[ks], acc, 0, 0, 0);
#pragma unroll
        for (int i = 0; i < 4; ++i) {
            int row = mt * 16 + quad * 4 + i;
            klds[row * LSTR + nt * 16 + l15] = f2bf(fmaxf(acc[i] + bias2, 0.f));
        }
    }
    __syncthreads();
    // S6: out = mid @ W3 + b3 (25 rows x 2)
    if (tid < TILE) {
        int r = tid;
        float o0 = b3[0], o1 = b3[1];
#pragma unroll
        for (int k = 0; k < MID_; ++k) {
            float mv = bf2f(klds[r * LSTR + k]);
            o0 += mv * W3[k * 2];
            o1 += mv * W3[k * 2 + 1];
        }
        float2* op = (float2*)(out + ((size_t)b * S_ + r0 + r) * OUT_);
        *op = make_float2(o0, o1);
    }
}

// ---------------------------------------------------------------------------
extern "C" void kernel_launch(void* const* d_in, const int* in_sizes, int n_in,
                              void* d_out, int out_size, void* d_ws, size_t ws_size,
                              hipStream_t stream) {
    const float* x  = (const float*)d_in[0];
    const float* W1 = (const float*)d_in[1];
    const float* b1 = (const float*)d_in[2];
    const float* Wq = (const float*)d_in[3];
    const float* Wk = (const float*)d_in[4];
    const float* Wv = (const float*)d_in[5];
    const float* bv = (const float*)d_in[6];
    const float* W2 = (const float*)d_in[7];
    const float* b2 = (const float*)d_in[8];
    const float* W3 = (const float*)d_in[9];
    const float* b3 = (const float*)d_in[10];
    const float* pe = (const float*)d_in[11];

    float* out  = (float*)d_out;             // (B,S,2)
    float* wout = out + (size_t)P_ * OUT_;   // (B,S,1,5)

    ushort* W1T  = (ushort*)d_ws;            // [128][128] bf16
    ushort* WqkT = W1T + 16384;
    ushort* WvT  = WqkT + 16384;
    ushort* W2T  = WvT + 16384;              // [32][128]

    prep_kernel<<<160, 256, 0, stream>>>(W1, Wv, W2, Wq, Wk, W1T, WvT, W2T, WqkT);
    fused_kernel<<<B_ * 4, 256, 0, stream>>>(x, W1T, WqkT, WvT, W2T,
                                             b1, bv, b2, W3, b3, pe, out, wout);
}